// Round 4
// baseline (90.848 us; speedup 1.0000x reference)
//
#include <hip/hip_runtime.h>

// LambdaRankLoss: B=64, N=1024, binary relevances, SIGMA=1, NDCG@10, EPS=1e-8.
// loss = (1/num_pairs) * sum_{valid b} sum_{i in rel, j in nonrel}
//            |disc_i - disc_j| / (idcg_b + eps) * softplus(s_j - s_i)
// valid b  <=>  0 < nrel_b < N ; idcg_b = sum_{p < min(nrel_b,10)} 1/log2(p+2)
//
// Structure (round 4): partition ONCE per batch (kernel 1, 64 blocks) into
// compacted global lists with disc pre-scaled by 1/idcg; pair kernel (64x16
// blocks) stages only its 4KB non-list + rel slice. Final reduction is done
// by the LAST pair-block (agent-scope done counter) in FIXED index order over
// deterministic per-block partials -> bitwise-deterministic result.

#define NPOS   1024
#define NCHUNK 16          // 16 chunks of one wave each
#define KTOP   10
#define EPSF   1e-8f
#define SPLIT2 16          // pair-blocks per batch; grid2 = 64*16 = 1024
#define MAXB   64

__device__ __forceinline__ float softplus_f(float z) {
    // log1p(exp(z)) stable: max(z,0) + log(1+exp(-|z|)); ~2% tol -> fast path
    return fmaxf(z, 0.0f) + __logf(1.0f + __expf(-fabsf(z)));
}

// ---- Kernel 1: one block per batch; stable partition + prescale + compact out
__global__ __launch_bounds__(256) void lr_partition_kernel(
    const float* __restrict__ scores,
    const int*   __restrict__ relev,
    float2*      __restrict__ relC,
    float2*      __restrict__ nonC,
    int*         __restrict__ nrelArr,
    unsigned*    __restrict__ pairsArr,
    unsigned*    __restrict__ done)
{
    __shared__ float2 rel2[NPOS];
    __shared__ float2 non2[NPOS];
    __shared__ int    cnt[NCHUNK];

    const int b = blockIdx.x, tid = threadIdx.x, lane = tid & 63, wave = tid >> 6;
    const float* srow = scores + (size_t)b * NPOS;
    const int*   rrow = relev  + (size_t)b * NPOS;

    // Phase 1: load + per-chunk ballot counts (chunk c handled by wave c&3)
    float sv[4], dv[4]; int rposv[4]; bool rf[4];
    #pragma unroll
    for (int it = 0; it < 4; ++it) {
        const int c = it * 4 + wave, idx = c * 64 + lane;
        sv[it] = srow[idx];
        dv[it] = 1.0f / log2f((float)idx + 2.0f);
        const bool r = rrow[idx] > 0; rf[it] = r;
        unsigned long long m = __ballot(r);
        rposv[it] = __popcll(m & ((1ull << lane) - 1ull));
        if (lane == 0) cnt[c] = __popcll(m);
    }
    __syncthreads();

    // Phase 2: deterministic stable scatter (base = exclusive scan of cnt[])
    #pragma unroll
    for (int it = 0; it < 4; ++it) {
        const int c = it * 4 + wave;
        int rbase = 0;
        for (int cc = 0; cc < c; ++cc) rbase += cnt[cc];
        const int nbase = c * 64 - rbase;
        if (rf[it]) rel2[rbase + rposv[it]]          = make_float2(sv[it], dv[it]);
        else        non2[nbase + (lane - rposv[it])] = make_float2(sv[it], dv[it]);
    }
    __syncthreads();

    int nrel = 0;
    #pragma unroll
    for (int c = 0; c < NCHUNK; ++c) nrel += cnt[c];
    const int nnon = NPOS - nrel;

    float idcg = 0.0f;
    const int kk = min(nrel, KTOP);
    for (int p = 0; p < kk; ++p) idcg += 1.0f / log2f((float)p + 2.0f);
    const float inv = 1.0f / (idcg + EPSF);

    // compact out, disc pre-scaled so pair kernel does delta = |da - db|
    for (int k = tid; k < nrel; k += 256) { float2 v = rel2[k]; v.y *= inv; relC[(size_t)b*NPOS + k] = v; }
    for (int k = tid; k < nnon; k += 256) { float2 v = non2[k]; v.y *= inv; nonC[(size_t)b*NPOS + k] = v; }

    if (tid == 0) {
        nrelArr[b]  = nrel;
        pairsArr[b] = (nrel > 0 && nnon > 0) ? (unsigned)(nrel * nnon) : 0u;
        if (b == 0) done[0] = 0u;   // visible to kernel 2 at launch boundary
    }
}

// ---- Kernel 2: 16 blocks per batch; pair loop + last-block fixed-order reduce
__global__ __launch_bounds__(256) void lr_pair_kernel(
    const float2*   __restrict__ relC,
    const float2*   __restrict__ nonC,
    const int*      __restrict__ nrelArr,
    const unsigned* __restrict__ pairsArr,
    double*         __restrict__ partials,
    unsigned*       __restrict__ done,
    float*          __restrict__ out,
    int nblocks)
{
    __shared__ float2 nshr[NPOS];
    __shared__ float2 rshr[64];       // slice <= ceil(1023/16) = 64
    __shared__ double wsum[4];
    __shared__ int    lastFlag;

    const int b = blockIdx.x / SPLIT2, slice = blockIdx.x % SPLIT2;
    const int tid = threadIdx.x, lane = tid & 63, wave = tid >> 6;

    const int nrel = nrelArr[b];
    const int nnon = NPOS - nrel;
    const int i0 = (slice * nrel) / SPLIT2;
    const int i1 = ((slice + 1) * nrel) / SPLIT2;
    const int ni = i1 - i0;

    double block_total = 0.0;
    if (nrel > 0 && nnon > 0 && ni > 0) {        // block-uniform condition
        for (int k = tid; k < nnon; k += 256) nshr[k] = nonC[(size_t)b*NPOS + k];
        for (int k = tid; k < ni;   k += 256) rshr[k] = relC[(size_t)b*NPOS + i0 + k];
        __syncthreads();

        // 4 independent accumulators break the fma dependence chain;
        // summation order is fixed -> deterministic.
        float acc0 = 0.f, acc1 = 0.f, acc2 = 0.f, acc3 = 0.f;
        int i = 0;
        for (; i + 4 <= ni; i += 4) {
            const float2 a0 = rshr[i], a1 = rshr[i+1], a2 = rshr[i+2], a3 = rshr[i+3];
            for (int j = tid; j < nnon; j += 256) {
                const float2 bj = nshr[j];           // one ds_read_b64 / 4 pairs
                acc0 += fabsf(a0.y - bj.y) * softplus_f(bj.x - a0.x);
                acc1 += fabsf(a1.y - bj.y) * softplus_f(bj.x - a1.x);
                acc2 += fabsf(a2.y - bj.y) * softplus_f(bj.x - a2.x);
                acc3 += fabsf(a3.y - bj.y) * softplus_f(bj.x - a3.x);
            }
        }
        for (; i < ni; ++i) {
            const float2 a0 = rshr[i];
            for (int j = tid; j < nnon; j += 256) {
                const float2 bj = nshr[j];
                acc0 += fabsf(a0.y - bj.y) * softplus_f(bj.x - a0.x);
            }
        }
        float acc = (acc0 + acc1) + (acc2 + acc3);

        // fixed-order wave shuffle reduce -> cross-wave LDS in double
        #pragma unroll
        for (int off = 32; off >= 1; off >>= 1) acc += __shfl_down(acc, off);
        if (lane == 0) wsum[wave] = (double)acc;
        __syncthreads();
        if (tid == 0) block_total = wsum[0] + wsum[1] + wsum[2] + wsum[3];
    }

    // publish partial (agent scope for cross-XCD visibility), bump done counter
    if (tid == 0) {
        __hip_atomic_store(&partials[blockIdx.x], block_total,
                           __ATOMIC_RELEASE, __HIP_MEMORY_SCOPE_AGENT);
        unsigned old = __hip_atomic_fetch_add(done, 1u,
                           __ATOMIC_ACQ_REL, __HIP_MEMORY_SCOPE_AGENT);
        lastFlag = (old == (unsigned)(nblocks - 1)) ? 1 : 0;
    }
    __syncthreads();

    if (lastFlag) {
        // FIXED-ORDER reduction: result is identical no matter which block
        // runs this -> bitwise deterministic across launches.
        double tot = 0.0;
        for (int k = tid; k < nblocks; k += 256)
            tot += __hip_atomic_load(&partials[k],
                       __ATOMIC_ACQUIRE, __HIP_MEMORY_SCOPE_AGENT);
        long long pairs = (tid < MAXB) ? (long long)pairsArr[tid] : 0;

        #pragma unroll
        for (int off = 32; off >= 1; off >>= 1) {
            tot   += __shfl_down(tot, off);
            pairs += __shfl_down(pairs, off);
        }
        __shared__ double    dsh[4];
        __shared__ long long psh[4];
        if (lane == 0) { dsh[wave] = tot; psh[wave] = pairs; }
        __syncthreads();
        if (tid == 0) {
            double    tt = dsh[0] + dsh[1] + dsh[2] + dsh[3];
            long long np = psh[0] + psh[1] + psh[2] + psh[3];
            out[0] = (np > 0) ? (float)(tt / (double)np) : 0.0f;
        }
    }
}

extern "C" void kernel_launch(void* const* d_in, const int* in_sizes, int n_in,
                              void* d_out, int out_size, void* d_ws, size_t ws_size,
                              hipStream_t stream) {
    const float* scores = (const float*)d_in[0];
    const int*   relev  = (const int*)d_in[1];
    float*       out    = (float*)d_out;
    const int    B      = in_sizes[0] / NPOS;   // 64
    const int    nblocks = B * SPLIT2;          // 1024

    // ws layout (all read slots are written every call; no memset needed)
    float2*   relC     = (float2*)d_ws;                    // 64*1024*8 = 512 KB
    float2*   nonC     = relC + (size_t)MAXB * NPOS;       // 512 KB
    int*      nrelArr  = (int*)(nonC + (size_t)MAXB * NPOS);
    unsigned* pairsArr = (unsigned*)(nrelArr + MAXB);
    double*   partials = (double*)(pairsArr + MAXB);       // 1024 doubles
    unsigned* done     = (unsigned*)(partials + nblocks);  // zeroed by kernel 1

    lr_partition_kernel<<<B, 256, 0, stream>>>(scores, relev, relC, nonC,
                                               nrelArr, pairsArr, done);
    lr_pair_kernel<<<nblocks, 256, 0, stream>>>(relC, nonC, nrelArr, pairsArr,
                                                partials, done, out, nblocks);
}

// Round 5
// 87.308 us; speedup vs baseline: 1.0405x; 1.0405x over previous
//
#include <hip/hip_runtime.h>

// LambdaRankLoss: B=64, N=1024, binary relevances, SIGMA=1, NDCG@10, EPS=1e-8.
// loss = (1/num_pairs) * sum_{valid b} sum_{i in rel, j in nonrel}
//            |disc_i - disc_j| / (idcg_b + eps) * softplus(s_j - s_i)
// valid b  <=>  0 < nrel_b < N ; idcg_b = sum_{p < min(nrel_b,10)} 1/log2(p+2)
//
// Round 5: ONE kernel (launch overhead dominated rounds 3/4). 64 batches x 16
// slices = 1024 blocks. Each block deterministically re-partitions its batch
// in LDS (ballot + chunk-count scan -> stable order, no atomics), computes its
// rel-slice x non-list pairs, release-stores a fixed-order partial, and the
// LAST block (agent-scope done counter) reduces all partials in FIXED index
// order -> bitwise-deterministic output (tripwire-safe).
// inv_idcg is factored out of the batch sum (applied once, in double).

#define NPOS   1024
#define SPLIT  16                      // slices per batch; grid = B*SPLIT
#define KTOP   10
#define EPSF   1e-8f
#define MAXSL  ((NPOS + SPLIT - 1) / SPLIT)   // 64 rel items per slice max

__device__ __forceinline__ float softplus_f(float z) {
    // log1p(exp(z)) stable: max(z,0) + log(1+exp(-|z|)); ~2% tol -> fast path
    return fmaxf(z, 0.0f) + __logf(1.0f + __expf(-fabsf(z)));
}

__global__ __launch_bounds__(256) void lr_fused_kernel(
    const float* __restrict__ scores,
    const int*   __restrict__ relev,
    unsigned*    __restrict__ ctl,       // [0]=done, [1]=pair count (memset 0)
    double*      __restrict__ partials,  // one slot per block
    float*       __restrict__ out,
    int nblocks)
{
    __shared__ float2 nshr[NPOS];        // nonrel (score, disc), stable order
    __shared__ float2 rshr[MAXSL];       // this slice's rel items
    __shared__ int    cnt[16];           // rel count per 64-item chunk
    __shared__ double wsum[4];
    __shared__ double dsh[4];
    __shared__ int    lastFlag;

    const int b     = blockIdx.x >> 4;           // SPLIT == 16
    const int slice = blockIdx.x & (SPLIT - 1);
    const int tid   = threadIdx.x;
    const int lane  = tid & 63;
    const int wave  = tid >> 6;

    const float* srow = scores + (size_t)b * NPOS;
    const int*   rrow = relev  + (size_t)b * NPOS;

    // ---- Phase 1: load + per-chunk ballot counts (chunk c -> wave c&3) ----
    float sv[4], dv[4]; int rposv[4]; bool rf[4];
    #pragma unroll
    for (int it = 0; it < 4; ++it) {
        const int c = it * 4 + wave, idx = c * 64 + lane;
        sv[it] = srow[idx];
        dv[it] = 1.0f / log2f((float)idx + 2.0f);
        const bool r = rrow[idx] > 0; rf[it] = r;
        unsigned long long m = __ballot(r);
        rposv[it] = __popcll(m & ((1ull << lane) - 1ull));
        if (lane == 0) cnt[c] = __popcll(m);
    }
    __syncthreads();

    int nrel = 0;
    #pragma unroll
    for (int c = 0; c < 16; ++c) nrel += cnt[c];  // uniform LDS broadcasts
    const int nnon = NPOS - nrel;
    const int i0 = (slice * nrel) / SPLIT;
    const int i1 = ((slice + 1) * nrel) / SPLIT;
    const int ni = i1 - i0;

    // ---- Phase 2: deterministic stable scatter (rel windowed to slice) ----
    #pragma unroll
    for (int it = 0; it < 4; ++it) {
        const int c = it * 4 + wave;
        int rbase = 0;
        for (int cc = 0; cc < c; ++cc) rbase += cnt[cc];
        if (rf[it]) {
            const int p = rbase + rposv[it];
            if (p >= i0 && p < i1) rshr[p - i0] = make_float2(sv[it], dv[it]);
        } else {
            nshr[c * 64 - rbase + (lane - rposv[it])] = make_float2(sv[it], dv[it]);
        }
    }
    __syncthreads();

    double block_total = 0.0;
    if (nrel > 0 && nnon > 0 && ni > 0) {        // block-uniform condition
        // 4 independent accumulators; fixed order -> deterministic
        float acc0 = 0.f, acc1 = 0.f, acc2 = 0.f, acc3 = 0.f;
        int i = 0;
        for (; i + 4 <= ni; i += 4) {
            const float2 a0 = rshr[i], a1 = rshr[i+1], a2 = rshr[i+2], a3 = rshr[i+3];
            for (int j = tid; j < nnon; j += 256) {
                const float2 bj = nshr[j];       // one ds_read_b64 / 4 pairs
                acc0 += fabsf(a0.y - bj.y) * softplus_f(bj.x - a0.x);
                acc1 += fabsf(a1.y - bj.y) * softplus_f(bj.x - a1.x);
                acc2 += fabsf(a2.y - bj.y) * softplus_f(bj.x - a2.x);
                acc3 += fabsf(a3.y - bj.y) * softplus_f(bj.x - a3.x);
            }
        }
        for (; i < ni; ++i) {
            const float2 a0 = rshr[i];
            for (int j = tid; j < nnon; j += 256) {
                const float2 bj = nshr[j];
                acc0 += fabsf(a0.y - bj.y) * softplus_f(bj.x - a0.x);
            }
        }
        float acc = (acc0 + acc1) + (acc2 + acc3);

        // fixed-order wave shuffle reduce -> cross-wave LDS in double
        #pragma unroll
        for (int off = 32; off >= 1; off >>= 1) acc += __shfl_down(acc, off);
        if (lane == 0) wsum[wave] = (double)acc;
        __syncthreads();
        if (tid == 0) {
            float idcg = 0.0f;
            const int kk = min(nrel, KTOP);
            for (int p = 0; p < kk; ++p) idcg += 1.0f / log2f((float)p + 2.0f);
            const double scale = (double)(1.0f / (idcg + EPSF));
            block_total = (wsum[0] + wsum[1] + wsum[2] + wsum[3]) * scale;
        }
    }

    // ---- publish partial + pair count; last-done block reduces ----
    if (tid == 0) {
        __hip_atomic_store(&partials[blockIdx.x], block_total,
                           __ATOMIC_RELEASE, __HIP_MEMORY_SCOPE_AGENT);
        if (slice == 0 && nrel > 0 && nnon > 0)
            __hip_atomic_fetch_add(&ctl[1], (unsigned)(nrel * nnon),
                                   __ATOMIC_RELAXED, __HIP_MEMORY_SCOPE_AGENT);
        unsigned old = __hip_atomic_fetch_add(&ctl[0], 1u,
                                   __ATOMIC_ACQ_REL, __HIP_MEMORY_SCOPE_AGENT);
        lastFlag = (old == (unsigned)(nblocks - 1)) ? 1 : 0;
    }
    __syncthreads();

    if (lastFlag) {
        // FIXED-ORDER reduction: identical result no matter which block is
        // last -> bitwise deterministic across launches.
        double tot = 0.0;
        for (int k = tid; k < nblocks; k += 256)
            tot += __hip_atomic_load(&partials[k],
                       __ATOMIC_ACQUIRE, __HIP_MEMORY_SCOPE_AGENT);
        #pragma unroll
        for (int off = 32; off >= 1; off >>= 1) tot += __shfl_down(tot, off);
        if (lane == 0) dsh[wave] = tot;
        __syncthreads();
        if (tid == 0) {
            unsigned np = __hip_atomic_load(&ctl[1],
                              __ATOMIC_RELAXED, __HIP_MEMORY_SCOPE_AGENT);
            double tt = dsh[0] + dsh[1] + dsh[2] + dsh[3];
            out[0] = (np > 0) ? (float)(tt / (double)np) : 0.0f;
        }
    }
}

extern "C" void kernel_launch(void* const* d_in, const int* in_sizes, int n_in,
                              void* d_out, int out_size, void* d_ws, size_t ws_size,
                              hipStream_t stream) {
    const float* scores = (const float*)d_in[0];
    const int*   relev  = (const int*)d_in[1];
    float*       out    = (float*)d_out;
    const int    B      = in_sizes[0] / NPOS;   // 64
    const int    nblocks = B * SPLIT;           // 1024

    unsigned* ctl      = (unsigned*)d_ws;                  // 16 B control
    double*   partials = (double*)((char*)d_ws + 16);      // nblocks doubles

    hipMemsetAsync(d_ws, 0, 16, stream);   // done=0, pairs=0 (graph-capturable)
    lr_fused_kernel<<<nblocks, 256, 0, stream>>>(scores, relev, ctl,
                                                 partials, out, nblocks);
}

// Round 6
// 73.705 us; speedup vs baseline: 1.2326x; 1.1846x over previous
//
#include <hip/hip_runtime.h>

// LambdaRankLoss: B=64, N=1024, binary relevances, SIGMA=1, NDCG@10, EPS=1e-8.
// loss = (1/num_pairs) * sum_{valid b} sum_{i in rel, j in nonrel}
//            |disc_i - disc_j| / (idcg_b + eps) * softplus(s_j - s_i)
// valid b  <=>  0 < nrel_b < N ; idcg_b = sum_{p < min(nrel_b,10)} 1/log2(p+2)
//
// Round 6 = Round 3 (best, 76 us) refined. Two kernels, NO device-scope
// atomic finale (R4/R5 showed it costs +11-15 us). Pair kernel: deterministic
// ballot+chunk-scan partition; rel items windowed to this slice only (LDS
// 16.9 -> 8.8 KB); no prescale pass (1/idcg folded in once, in double, at
// block end); 4-accumulator ILP hot loop. All reductions fixed-order;
// per-block partial slots; tiny fixed-order final kernel. Bitwise
// deterministic -> tripwire-safe.

#define NPOS   1024
#define SPLIT  16                      // slices per batch; grid = B*SPLIT
#define KTOP   10
#define EPSF   1e-8f
#define MAXSL  ((NPOS + SPLIT - 1) / SPLIT)   // 64 rel items per slice max
#define MAXB   64

__device__ __forceinline__ float softplus_f(float z) {
    // log1p(exp(z)) stable: max(z,0) + log(1+exp(-|z|)); ~2% tol -> fast path
    return fmaxf(z, 0.0f) + __logf(1.0f + __expf(-fabsf(z)));
}

__global__ __launch_bounds__(256) void lr_pair_kernel(
    const float* __restrict__ scores,
    const int*   __restrict__ relev,
    double*      __restrict__ partials,   // one slot per block
    unsigned*    __restrict__ pairCnt)    // one slot per batch (slice 0 writes)
{
    __shared__ float2 nshr[NPOS];        // nonrel (score, disc), stable order
    __shared__ float2 rshr[MAXSL];       // this slice's rel items only
    __shared__ int    cnt[16];           // rel count per 64-item chunk
    __shared__ double wsum[4];

    const int b     = blockIdx.x >> 4;           // SPLIT == 16
    const int slice = blockIdx.x & (SPLIT - 1);
    const int tid   = threadIdx.x;
    const int lane  = tid & 63;
    const int wave  = tid >> 6;

    const float* srow = scores + (size_t)b * NPOS;
    const int*   rrow = relev  + (size_t)b * NPOS;

    // ---- Phase 1: load + per-chunk ballot counts (chunk c -> wave c&3) ----
    float sv[4], dv[4]; int rposv[4]; bool rf[4];
    #pragma unroll
    for (int it = 0; it < 4; ++it) {
        const int c = it * 4 + wave, idx = c * 64 + lane;
        sv[it] = srow[idx];
        dv[it] = 1.0f / log2f((float)idx + 2.0f);
        const bool r = rrow[idx] > 0; rf[it] = r;
        unsigned long long m = __ballot(r);
        rposv[it] = __popcll(m & ((1ull << lane) - 1ull));
        if (lane == 0) cnt[c] = __popcll(m);
    }
    __syncthreads();

    int nrel = 0;
    #pragma unroll
    for (int c = 0; c < 16; ++c) nrel += cnt[c];  // uniform LDS broadcasts
    const int nnon = NPOS - nrel;
    const int i0 = (slice * nrel) / SPLIT;
    const int i1 = ((slice + 1) * nrel) / SPLIT;
    const int ni = i1 - i0;

    // ---- Phase 2: deterministic stable scatter (rel windowed to slice) ----
    #pragma unroll
    for (int it = 0; it < 4; ++it) {
        const int c = it * 4 + wave;
        int rbase = 0;
        for (int cc = 0; cc < c; ++cc) rbase += cnt[cc];
        if (rf[it]) {
            const int p = rbase + rposv[it];
            if (p >= i0 && p < i1) rshr[p - i0] = make_float2(sv[it], dv[it]);
        } else {
            nshr[c * 64 - rbase + (lane - rposv[it])] = make_float2(sv[it], dv[it]);
        }
    }
    __syncthreads();

    double block_total = 0.0;
    if (nrel > 0 && nnon > 0 && ni > 0) {        // block-uniform condition
        // 4 independent accumulators; fixed order -> deterministic
        float acc0 = 0.f, acc1 = 0.f, acc2 = 0.f, acc3 = 0.f;
        int i = 0;
        for (; i + 4 <= ni; i += 4) {
            const float2 a0 = rshr[i], a1 = rshr[i+1], a2 = rshr[i+2], a3 = rshr[i+3];
            for (int j = tid; j < nnon; j += 256) {
                const float2 bj = nshr[j];       // one ds_read_b64 / 4 pairs
                acc0 += fabsf(a0.y - bj.y) * softplus_f(bj.x - a0.x);
                acc1 += fabsf(a1.y - bj.y) * softplus_f(bj.x - a1.x);
                acc2 += fabsf(a2.y - bj.y) * softplus_f(bj.x - a2.x);
                acc3 += fabsf(a3.y - bj.y) * softplus_f(bj.x - a3.x);
            }
        }
        for (; i < ni; ++i) {
            const float2 a0 = rshr[i];
            for (int j = tid; j < nnon; j += 256) {
                const float2 bj = nshr[j];
                acc0 += fabsf(a0.y - bj.y) * softplus_f(bj.x - a0.x);
            }
        }
        float acc = (acc0 + acc1) + (acc2 + acc3);

        // fixed-order wave shuffle reduce -> cross-wave LDS in double
        #pragma unroll
        for (int off = 32; off >= 1; off >>= 1) acc += __shfl_down(acc, off);
        if (lane == 0) wsum[wave] = (double)acc;
        __syncthreads();
        if (tid == 0) {
            float idcg = 0.0f;
            const int kk = min(nrel, KTOP);
            for (int p = 0; p < kk; ++p) idcg += 1.0f / log2f((float)p + 2.0f);
            block_total = (wsum[0] + wsum[1] + wsum[2] + wsum[3])
                        * (double)(1.0f / (idcg + EPSF));
        }
    }

    if (tid == 0) {
        partials[blockIdx.x] = block_total;      // own slot, plain store
        if (slice == 0)
            pairCnt[b] = (nrel > 0 && nnon > 0) ? (unsigned)(nrel * nnon) : 0u;
    }
}

__global__ __launch_bounds__(256) void lr_final_kernel(
    const double*   __restrict__ partials,
    const unsigned* __restrict__ pairCnt,
    float*          __restrict__ out,
    int B, int nparts)
{
    __shared__ double    dsh[4];
    __shared__ long long psh[4];

    const int tid = threadIdx.x, lane = tid & 63, wave = tid >> 6;

    // fixed-order per-thread partial sums (nparts = 1024 = 4*256)
    double tot = 0.0;
    for (int k = tid; k < nparts; k += 256) tot += partials[k];
    long long pairs = (tid < B) ? (long long)pairCnt[tid] : 0;

    #pragma unroll
    for (int off = 32; off >= 1; off >>= 1) {
        tot   += __shfl_down(tot, off);
        pairs += __shfl_down(pairs, off);
    }
    if (lane == 0) { dsh[wave] = tot; psh[wave] = pairs; }
    __syncthreads();
    if (tid == 0) {
        double    tt = dsh[0] + dsh[1] + dsh[2] + dsh[3];
        long long np = psh[0] + psh[1] + psh[2] + psh[3];
        out[0] = (np > 0) ? (float)(tt / (double)np) : 0.0f;
    }
}

extern "C" void kernel_launch(void* const* d_in, const int* in_sizes, int n_in,
                              void* d_out, int out_size, void* d_ws, size_t ws_size,
                              hipStream_t stream) {
    const float* scores = (const float*)d_in[0];
    const int*   relev  = (const int*)d_in[1];
    float*       out    = (float*)d_out;
    const int    B      = in_sizes[0] / NPOS;   // 64
    const int    nparts = B * SPLIT;            // 1024

    double*   partials = (double*)d_ws;                    // nparts doubles
    unsigned* pairCnt  = (unsigned*)(partials + nparts);   // B uints
    // every read slot is written by lr_pair_kernel each call: no memset

    lr_pair_kernel<<<nparts, 256, 0, stream>>>(scores, relev, partials, pairCnt);
    lr_final_kernel<<<1, 256, 0, stream>>>(partials, pairCnt, out, B, nparts);
}

// Round 7
// 71.681 us; speedup vs baseline: 1.2674x; 1.0282x over previous
//
#include <hip/hip_runtime.h>

// LambdaRankLoss: B=64, N=1024, binary relevances, SIGMA=1, NDCG@10, EPS=1e-8.
// loss = (1/num_pairs) * sum_{valid b} sum_{i in rel, j in nonrel}
//            |disc_i - disc_j| / (idcg_b + eps) * softplus(s_j - s_i)
// valid b  <=>  0 < nrel_b < N ; idcg_b = sum_{p < min(nrel_b,10)} 1/log2(p+2)
//
// Round 7 = Round 6 (best, 73.7 us) with the pair kernel trimmed:
//  - fast __log2f + v_rcp for discounts/idcg (was libm log2f + IEEE divide:
//    ~40 inst/value -> ~2; tolerance budget is ~2% so precision was waste)
//  - incremental chunk-prefix scan (60 uniform LDS reads -> <=15)
//  - idcg computed by all threads BEFORE the hot loop (no tid0 serial tail)
// Two kernels, plain per-block partial stores, fixed-order reductions
// everywhere -> bitwise deterministic (tripwire-safe). No memset needed.

#define NPOS   1024
#define SPLIT  16                      // slices per batch; grid = B*SPLIT
#define KTOP   10
#define EPSF   1e-8f
#define MAXSL  ((NPOS + SPLIT - 1) / SPLIT)   // 64 rel items per slice max
#define MAXB   64

__device__ __forceinline__ float softplus_f(float z) {
    // log1p(exp(z)) stable: max(z,0) + log(1+exp(-|z|)); ~2% tol -> fast path
    return fmaxf(z, 0.0f) + __logf(1.0f + __expf(-fabsf(z)));
}

__device__ __forceinline__ float inv_log2_f(float x) {
    // 1/log2(x), fast: v_log_f32 + v_rcp_f32 (~1e-5 rel err, fine vs 2% tol)
    return __builtin_amdgcn_rcpf(__log2f(x));
}

__global__ __launch_bounds__(256) void lr_pair_kernel(
    const float* __restrict__ scores,
    const int*   __restrict__ relev,
    double*      __restrict__ partials,   // one slot per block
    unsigned*    __restrict__ pairCnt)    // one slot per batch (slice 0 writes)
{
    __shared__ float2 nshr[NPOS];        // nonrel (score, disc), stable order
    __shared__ float2 rshr[MAXSL];       // this slice's rel items only
    __shared__ int    cnt[16];           // rel count per 64-item chunk
    __shared__ double wsum[4];

    const int b     = blockIdx.x >> 4;           // SPLIT == 16
    const int slice = blockIdx.x & (SPLIT - 1);
    const int tid   = threadIdx.x;
    const int lane  = tid & 63;
    const int wave  = tid >> 6;

    const float* srow = scores + (size_t)b * NPOS;
    const int*   rrow = relev  + (size_t)b * NPOS;

    // ---- Phase 1: load + per-chunk ballot counts (chunk c -> wave c&3) ----
    float sv[4], dv[4]; int rposv[4]; bool rf[4];
    #pragma unroll
    for (int it = 0; it < 4; ++it) {
        const int c = it * 4 + wave, idx = c * 64 + lane;
        sv[it] = srow[idx];
        dv[it] = inv_log2_f((float)idx + 2.0f);
        const bool r = rrow[idx] > 0; rf[it] = r;
        unsigned long long m = __ballot(r);
        rposv[it] = __popcll(m & ((1ull << lane) - 1ull));
        if (lane == 0) cnt[c] = __popcll(m);
    }
    __syncthreads();

    int nrel = 0;
    #pragma unroll
    for (int c = 0; c < 16; ++c) nrel += cnt[c];  // uniform LDS broadcasts
    const int nnon = NPOS - nrel;
    const int i0 = (slice * nrel) / SPLIT;
    const int i1 = ((slice + 1) * nrel) / SPLIT;
    const int ni = i1 - i0;

    // ---- Phase 2: deterministic stable scatter, incremental prefix scan ----
    {
        int rb = 0;                                   // sum cnt[0 .. c-1]
        for (int cc = 0; cc < wave; ++cc) rb += cnt[cc];
        #pragma unroll
        for (int it = 0; it < 4; ++it) {
            const int c = it * 4 + wave;
            if (rf[it]) {
                const int p = rb + rposv[it];
                if (p >= i0 && p < i1) rshr[p - i0] = make_float2(sv[it], dv[it]);
            } else {
                nshr[c * 64 - rb + (lane - rposv[it])] = make_float2(sv[it], dv[it]);
            }
            if (it < 3) rb += cnt[c] + cnt[c+1] + cnt[c+2] + cnt[c+3];
        }
    }

    // idcg by ALL threads (uniform, overlaps the barrier; no tid0 tail later)
    float idcg = 0.0f;
    {
        const int kk = min(nrel, KTOP);
        for (int p = 0; p < kk; ++p) idcg += inv_log2_f((float)p + 2.0f);
    }
    __syncthreads();

    double block_total = 0.0;
    if (nrel > 0 && nnon > 0 && ni > 0) {        // block-uniform condition
        // 4 independent accumulators; fixed order -> deterministic
        float acc0 = 0.f, acc1 = 0.f, acc2 = 0.f, acc3 = 0.f;
        int i = 0;
        for (; i + 4 <= ni; i += 4) {
            const float2 a0 = rshr[i], a1 = rshr[i+1], a2 = rshr[i+2], a3 = rshr[i+3];
            for (int j = tid; j < nnon; j += 256) {
                const float2 bj = nshr[j];       // one ds_read_b64 / 4 pairs
                acc0 += fabsf(a0.y - bj.y) * softplus_f(bj.x - a0.x);
                acc1 += fabsf(a1.y - bj.y) * softplus_f(bj.x - a1.x);
                acc2 += fabsf(a2.y - bj.y) * softplus_f(bj.x - a2.x);
                acc3 += fabsf(a3.y - bj.y) * softplus_f(bj.x - a3.x);
            }
        }
        for (; i < ni; ++i) {
            const float2 a0 = rshr[i];
            for (int j = tid; j < nnon; j += 256) {
                const float2 bj = nshr[j];
                acc0 += fabsf(a0.y - bj.y) * softplus_f(bj.x - a0.x);
            }
        }
        float acc = (acc0 + acc1) + (acc2 + acc3);

        // fixed-order wave shuffle reduce -> cross-wave LDS in double
        #pragma unroll
        for (int off = 32; off >= 1; off >>= 1) acc += __shfl_down(acc, off);
        if (lane == 0) wsum[wave] = (double)acc;
        __syncthreads();
        if (tid == 0)
            block_total = (wsum[0] + wsum[1] + wsum[2] + wsum[3])
                        * (double)(1.0f / (idcg + EPSF));
    }

    if (tid == 0) {
        partials[blockIdx.x] = block_total;      // own slot, plain store
        if (slice == 0)
            pairCnt[b] = (nrel > 0 && nnon > 0) ? (unsigned)(nrel * nnon) : 0u;
    }
}

__global__ __launch_bounds__(256) void lr_final_kernel(
    const double*   __restrict__ partials,
    const unsigned* __restrict__ pairCnt,
    float*          __restrict__ out,
    int B, int nparts)
{
    __shared__ double    dsh[4];
    __shared__ long long psh[4];

    const int tid = threadIdx.x, lane = tid & 63, wave = tid >> 6;

    // fixed-order per-thread partial sums (nparts = 1024 = 4*256)
    double tot = 0.0;
    for (int k = tid; k < nparts; k += 256) tot += partials[k];
    long long pairs = (tid < B) ? (long long)pairCnt[tid] : 0;

    #pragma unroll
    for (int off = 32; off >= 1; off >>= 1) {
        tot   += __shfl_down(tot, off);
        pairs += __shfl_down(pairs, off);
    }
    if (lane == 0) { dsh[wave] = tot; psh[wave] = pairs; }
    __syncthreads();
    if (tid == 0) {
        double    tt = dsh[0] + dsh[1] + dsh[2] + dsh[3];
        long long np = psh[0] + psh[1] + psh[2] + psh[3];
        out[0] = (np > 0) ? (float)(tt / (double)np) : 0.0f;
    }
}

extern "C" void kernel_launch(void* const* d_in, const int* in_sizes, int n_in,
                              void* d_out, int out_size, void* d_ws, size_t ws_size,
                              hipStream_t stream) {
    const float* scores = (const float*)d_in[0];
    const int*   relev  = (const int*)d_in[1];
    float*       out    = (float*)d_out;
    const int    B      = in_sizes[0] / NPOS;   // 64
    const int    nparts = B * SPLIT;            // 1024

    double*   partials = (double*)d_ws;                    // nparts doubles
    unsigned* pairCnt  = (unsigned*)(partials + nparts);   // B uints
    // every read slot is written by lr_pair_kernel each call: no memset

    lr_pair_kernel<<<nparts, 256, 0, stream>>>(scores, relev, partials, pairCnt);
    lr_final_kernel<<<1, 256, 0, stream>>>(partials, pairCnt, out, B, nparts);
}

// Round 8
// 67.634 us; speedup vs baseline: 1.3432x; 1.0598x over previous
//
#include <hip/hip_runtime.h>

// LambdaRankLoss: B=64, N=1024, binary relevances, SIGMA=1, NDCG@10, EPS=1e-8.
// loss = (1/num_pairs) * sum_{valid b} sum_{i in rel, j in nonrel}
//            |disc_i - disc_j| / (idcg_b + eps) * softplus(s_j - s_i)
// valid b  <=>  0 < nrel_b < N ; idcg_b = sum_{p < min(nrel_b,10)} 1/log2(p+2)
//
// Round 8 = Round 7 (71.7 us) with a hot-loop arithmetic diet:
//  - softplus via cubic log1p fit (no v_log per pair; abs err <= 3.3e-4,
//    -> loss err ~7e-6, 15x under the 1.1e-4 threshold)
//  - float4 LDS reads: 2 nonrel items per j-iteration (ds_read_b128),
//    halves LDS op count + loop overhead; odd-nnon tail done deterministically
//  - idcg from constant prefix table (binary gains): no transcendental loop
// Two kernels, plain per-block partial stores, fixed-order reductions
// everywhere -> bitwise deterministic (tripwire-safe). No memset needed.

#define NPOS   1024
#define SPLIT  16                      // slices per batch; grid = B*SPLIT
#define KTOP   10
#define EPSF   1e-8f
#define MAXSL  ((NPOS + SPLIT - 1) / SPLIT)   // 64 rel items per slice max
#define MAXB   64

// prefix sums of 1/log2(p+2), p=0..9: idcg = IDCG_S[min(nrel,10)]
__device__ const float IDCG_S[11] = {
    0.0f, 1.0f, 1.63092975f, 2.13092975f, 2.56160631f, 2.94845912f,
    3.30466631f, 3.63799964f, 3.95346452f, 4.25449452f, 4.54355935f
};

__device__ __forceinline__ float softplus_f(float z) {
    // max(z,0) + log1p(exp(-|z|)); log1p via cubic-in-g fit on (0,1]
    // (Chebyshev-node interpolation of log1p(t)/t; abs err <= ~3.3e-4)
    const float t = __expf(-fabsf(z));
    const float f = t * (0.999668f + t * (-0.486393f
                  + t * (0.253442f + t * (-0.073805f))));
    return fmaxf(z, 0.0f) + f;
}

__device__ __forceinline__ float inv_log2_f(float x) {
    // 1/log2(x), fast: v_log_f32 + v_rcp_f32 (~1e-5 rel err, fine vs budget)
    return __builtin_amdgcn_rcpf(__log2f(x));
}

__global__ __launch_bounds__(256) void lr_pair_kernel(
    const float* __restrict__ scores,
    const int*   __restrict__ relev,
    double*      __restrict__ partials,   // one slot per block
    unsigned*    __restrict__ pairCnt)    // one slot per batch (slice 0 writes)
{
    __shared__ __align__(16) float2 nshr[NPOS];  // nonrel (score, disc)
    __shared__ float2 rshr[MAXSL];       // this slice's rel items only
    __shared__ int    cnt[16];           // rel count per 64-item chunk
    __shared__ double wsum[4];

    const int b     = blockIdx.x >> 4;           // SPLIT == 16
    const int slice = blockIdx.x & (SPLIT - 1);
    const int tid   = threadIdx.x;
    const int lane  = tid & 63;
    const int wave  = tid >> 6;

    const float* srow = scores + (size_t)b * NPOS;
    const int*   rrow = relev  + (size_t)b * NPOS;

    // ---- Phase 1: load + per-chunk ballot counts (chunk c -> wave c&3) ----
    float sv[4], dv[4]; int rposv[4]; bool rf[4];
    #pragma unroll
    for (int it = 0; it < 4; ++it) {
        const int c = it * 4 + wave, idx = c * 64 + lane;
        sv[it] = srow[idx];
        dv[it] = inv_log2_f((float)idx + 2.0f);
        const bool r = rrow[idx] > 0; rf[it] = r;
        unsigned long long m = __ballot(r);
        rposv[it] = __popcll(m & ((1ull << lane) - 1ull));
        if (lane == 0) cnt[c] = __popcll(m);
    }
    __syncthreads();

    int nrel = 0;
    #pragma unroll
    for (int c = 0; c < 16; ++c) nrel += cnt[c];  // uniform LDS broadcasts
    const int nnon = NPOS - nrel;
    const int i0 = (slice * nrel) / SPLIT;
    const int i1 = ((slice + 1) * nrel) / SPLIT;
    const int ni = i1 - i0;

    // ---- Phase 2: deterministic stable scatter, incremental prefix scan ----
    {
        int rb = 0;                                   // sum cnt[0 .. c-1]
        for (int cc = 0; cc < wave; ++cc) rb += cnt[cc];
        #pragma unroll
        for (int it = 0; it < 4; ++it) {
            const int c = it * 4 + wave;
            if (rf[it]) {
                const int p = rb + rposv[it];
                if (p >= i0 && p < i1) rshr[p - i0] = make_float2(sv[it], dv[it]);
            } else {
                nshr[c * 64 - rb + (lane - rposv[it])] = make_float2(sv[it], dv[it]);
            }
            if (it < 3) rb += cnt[c] + cnt[c+1] + cnt[c+2] + cnt[c+3];
        }
    }

    const float idcg = IDCG_S[min(nrel, KTOP)];   // uniform table load
    __syncthreads();

    double block_total = 0.0;
    if (nrel > 0 && nnon > 0 && ni > 0) {        // block-uniform condition
        const float4* nshr4 = reinterpret_cast<const float4*>(nshr);
        const int nnon2 = nnon >> 1;

        // 4 independent accumulators; fixed order -> deterministic
        float acc0 = 0.f, acc1 = 0.f, acc2 = 0.f, acc3 = 0.f;
        int i = 0;
        for (; i + 4 <= ni; i += 4) {
            const float2 a0 = rshr[i], a1 = rshr[i+1], a2 = rshr[i+2], a3 = rshr[i+3];
            for (int jj = tid; jj < nnon2; jj += 256) {
                const float4 q = nshr4[jj];      // 2 items per ds_read_b128
                acc0 += fabsf(a0.y - q.y) * softplus_f(q.x - a0.x);
                acc1 += fabsf(a1.y - q.y) * softplus_f(q.x - a1.x);
                acc2 += fabsf(a2.y - q.y) * softplus_f(q.x - a2.x);
                acc3 += fabsf(a3.y - q.y) * softplus_f(q.x - a3.x);
                acc0 += fabsf(a0.y - q.w) * softplus_f(q.z - a0.x);
                acc1 += fabsf(a1.y - q.w) * softplus_f(q.z - a1.x);
                acc2 += fabsf(a2.y - q.w) * softplus_f(q.z - a2.x);
                acc3 += fabsf(a3.y - q.w) * softplus_f(q.z - a3.x);
            }
        }
        for (; i < ni; ++i) {
            const float2 a0 = rshr[i];
            for (int jj = tid; jj < nnon2; jj += 256) {
                const float4 q = nshr4[jj];
                acc0 += fabsf(a0.y - q.y) * softplus_f(q.x - a0.x);
                acc1 += fabsf(a0.y - q.w) * softplus_f(q.z - a0.x);
            }
        }
        if (nnon & 1) {                          // odd tail: one pair/thread
            const float2 bj = nshr[nnon - 1];
            if (tid < ni) {
                const float2 a = rshr[tid];
                acc0 += fabsf(a.y - bj.y) * softplus_f(bj.x - a.x);
            }
        }
        float acc = (acc0 + acc1) + (acc2 + acc3);

        // fixed-order wave shuffle reduce -> cross-wave LDS in double
        #pragma unroll
        for (int off = 32; off >= 1; off >>= 1) acc += __shfl_down(acc, off);
        if (lane == 0) wsum[wave] = (double)acc;
        __syncthreads();
        if (tid == 0)
            block_total = (wsum[0] + wsum[1] + wsum[2] + wsum[3])
                        * (double)(1.0f / (idcg + EPSF));
    }

    if (tid == 0) {
        partials[blockIdx.x] = block_total;      // own slot, plain store
        if (slice == 0)
            pairCnt[b] = (nrel > 0 && nnon > 0) ? (unsigned)(nrel * nnon) : 0u;
    }
}

__global__ __launch_bounds__(256) void lr_final_kernel(
    const double*   __restrict__ partials,
    const unsigned* __restrict__ pairCnt,
    float*          __restrict__ out,
    int B, int nparts)
{
    __shared__ double    dsh[4];
    __shared__ long long psh[4];

    const int tid = threadIdx.x, lane = tid & 63, wave = tid >> 6;

    // fixed-order per-thread partial sums (nparts = 1024 = 4*256)
    double tot = 0.0;
    for (int k = tid; k < nparts; k += 256) tot += partials[k];
    long long pairs = (tid < B) ? (long long)pairCnt[tid] : 0;

    #pragma unroll
    for (int off = 32; off >= 1; off >>= 1) {
        tot   += __shfl_down(tot, off);
        pairs += __shfl_down(pairs, off);
    }
    if (lane == 0) { dsh[wave] = tot; psh[wave] = pairs; }
    __syncthreads();
    if (tid == 0) {
        double    tt = dsh[0] + dsh[1] + dsh[2] + dsh[3];
        long long np = psh[0] + psh[1] + psh[2] + psh[3];
        out[0] = (np > 0) ? (float)(tt / (double)np) : 0.0f;
    }
}

extern "C" void kernel_launch(void* const* d_in, const int* in_sizes, int n_in,
                              void* d_out, int out_size, void* d_ws, size_t ws_size,
                              hipStream_t stream) {
    const float* scores = (const float*)d_in[0];
    const int*   relev  = (const int*)d_in[1];
    float*       out    = (float*)d_out;
    const int    B      = in_sizes[0] / NPOS;   // 64
    const int    nparts = B * SPLIT;            // 1024

    double*   partials = (double*)d_ws;                    // nparts doubles
    unsigned* pairCnt  = (unsigned*)(partials + nparts);   // B uints
    // every read slot is written by lr_pair_kernel each call: no memset

    lr_pair_kernel<<<nparts, 256, 0, stream>>>(scores, relev, partials, pairCnt);
    lr_final_kernel<<<1, 256, 0, stream>>>(partials, pairCnt, out, B, nparts);
}